// Round 1
// 12.314 us; speedup vs baseline: 1.2428x; 1.2428x over previous
//
#include <hip/hip_runtime.h>

#define NQ 2048
#define NP 64
#define DIM 1024
#define QB 16                  // queries per block
#define PB 32                  // protos per block
#define NW 8                   // waves per block = K-split factor
#define KW (DIM / NW)          // 128 K per wave
#define DROW 33                // padded per-q stride in dot scratch (bank-conflict-free)

typedef __attribute__((ext_vector_type(8))) short short8;   // bf16x8 MFMA fragment
typedef __attribute__((ext_vector_type(4))) float f32x4;    // MFMA accumulator

__device__ inline unsigned short f2bf(float f) {
    unsigned u = __builtin_bit_cast(unsigned, f);
    return (unsigned short)((u + 0x7fff + ((u >> 16) & 1)) >> 16);   // RNE
}

// convert 8 consecutive f32 to a bf16x8 fragment, accumulating sum-of-squares
__device__ inline short8 pack8(float4 a, float4 b, float& ss) {
    ss += a.x * a.x + a.y * a.y + a.z * a.z + a.w * a.w
        + b.x * b.x + b.y * b.y + b.z * b.z + b.w * b.w;
    short8 r;
    r[0] = (short)f2bf(a.x); r[1] = (short)f2bf(a.y);
    r[2] = (short)f2bf(a.z); r[3] = (short)f2bf(a.w);
    r[4] = (short)f2bf(b.x); r[5] = (short)f2bf(b.y);
    r[6] = (short)f2bf(b.z); r[7] = (short)f2bf(b.w);
    return r;
}

// One fused kernel: ||q-p||^2 = qn + pn - 2*q.p
// Block = 16 q x 32 p; 8 waves K-split DIM into 8x128; no global workspace.
// Fragments are loaded straight from global (lanes {r,r+16,r+32,r+48} cover one
// contiguous 128B row segment -> same cache lines as a coalesced load), so there
// is no LDS staging and no barrier until the final reduce.
__global__ __launch_bounds__(512)
void l2_fused(const float* __restrict__ proto,
              const float* __restrict__ query,
              float* __restrict__ out)
{
    __shared__ float dotl[NW][QB * DROW];   // 8 * 528 * 4 B = 16.9 KB
    __shared__ float qnl[NW][QB];
    __shared__ float pnl[NW][PB];

    const int tid = threadIdx.x;
    const int bq  = blockIdx.x & 127;       // bid and bid+128 share the q-tile
    const int bp  = blockIdx.x >> 7;        //   -> same XCD under %8 round-robin
    const int q0  = bq * QB;
    const int p0  = bp * PB;
    const int w   = tid >> 6;               // wave id = K-slice id
    const int l   = tid & 63;
    const int lo  = l & 15;
    const int hi  = l >> 4;

    // A frag: lane l holds Q[q0+lo][w*KW + s*32 + hi*8 .. +7]
    // B frag: lane l holds P[p0+t*16+lo][same k range]
    const float* qrow  = query + (size_t)(q0 + lo) * DIM + w * KW + hi * 8;
    const float* prow0 = proto + (size_t)(p0 + lo) * DIM + w * KW + hi * 8;
    const float* prow1 = prow0 + (size_t)16 * DIM;

    f32x4 acc0 = {0.f, 0.f, 0.f, 0.f};
    f32x4 acc1 = {0.f, 0.f, 0.f, 0.f};
    float qn = 0.f, pn0 = 0.f, pn1 = 0.f;

    #pragma unroll
    for (int s = 0; s < KW / 32; ++s) {
        float4 a0 = *(const float4*)(qrow  + s * 32);
        float4 a1 = *(const float4*)(qrow  + s * 32 + 4);
        float4 c0 = *(const float4*)(prow0 + s * 32);
        float4 c1 = *(const float4*)(prow0 + s * 32 + 4);
        float4 d0 = *(const float4*)(prow1 + s * 32);
        float4 d1 = *(const float4*)(prow1 + s * 32 + 4);
        short8 A  = pack8(a0, a1, qn);
        short8 B0 = pack8(c0, c1, pn0);
        short8 B1 = pack8(d0, d1, pn1);
        acc0 = __builtin_amdgcn_mfma_f32_16x16x32_bf16(A, B0, acc0, 0, 0, 0);
        acc1 = __builtin_amdgcn_mfma_f32_16x16x32_bf16(A, B1, acc1, 0, 0, 0);
    }

    // reduce norm partials across the 4 hi-groups sharing a row (lanes l^16, l^32)
    qn  += __shfl_xor(qn, 16);  qn  += __shfl_xor(qn, 32);
    pn0 += __shfl_xor(pn0, 16); pn0 += __shfl_xor(pn0, 32);
    pn1 += __shfl_xor(pn1, 16); pn1 += __shfl_xor(pn1, 32);
    if (l < 16) {
        qnl[w][l]      = qn;
        pnl[w][l]      = pn0;
        pnl[w][l + 16] = pn1;
    }

    // D layout: col = l&15 (proto), row = (l>>4)*4 + r (query)
    #pragma unroll
    for (int r = 0; r < 4; ++r) {
        int q = hi * 4 + r;
        dotl[w][q * DROW + lo]      = acc0[r];
        dotl[w][q * DROW + lo + 16] = acc1[r];
    }
    __syncthreads();

    // epilogue: 512 threads -> 512 outputs of this block
    const int q = tid >> 5;
    const int p = tid & 31;
    float dsum = 0.f, qs = 0.f, ps = 0.f;
    #pragma unroll
    for (int k = 0; k < NW; ++k) {
        dsum += dotl[k][q * DROW + p];
        qs   += qnl[k][q];
        ps   += pnl[k][p];
    }
    out[(size_t)(q0 + q) * NP + p0 + p] = qs + ps - 2.f * dsum;
}

extern "C" void kernel_launch(void* const* d_in, const int* in_sizes, int n_in,
                              void* d_out, int out_size, void* d_ws, size_t ws_size,
                              hipStream_t stream) {
    const float* proto = (const float*)d_in[0];
    const float* query = (const float*)d_in[1];
    (void)d_ws; (void)ws_size;
    l2_fused<<<dim3((NQ / QB) * (NP / PB)), 512, 0, stream>>>(proto, query, (float*)d_out);
}

// Round 2
// 12.141 us; speedup vs baseline: 1.2605x; 1.0142x over previous
//
#include <hip/hip_runtime.h>

#define NQ 2048
#define NP 64
#define DIM 1024
#define QB 16                  // queries per block
#define PB 32                  // protos per block
#define NW 8                   // waves per block = K-split factor
#define KW (DIM / NW)          // 128 K per wave
#define DROW 33                // padded per-q stride in dot scratch

typedef __attribute__((ext_vector_type(8))) short short8;     // bf16x8 MFMA fragment
typedef __attribute__((ext_vector_type(4))) float f32x4;      // MFMA accumulator
typedef __attribute__((ext_vector_type(4))) unsigned int u32x4;

// v_cvt_pk_bf16_f32: D = {hi: bf16(s1), lo: bf16(s0)}, RNE. No builtin on gfx950.
__device__ inline unsigned cvt_pk_bf16(float lo, float hi) {
    unsigned r;
    asm("v_cvt_pk_bf16_f32 %0, %1, %2" : "=v"(r) : "v"(lo), "v"(hi));
    return r;
}

// 8 consecutive f32 -> bf16x8 fragment (4 cvt_pk) + accumulate sum-of-squares
__device__ inline short8 pack8(float4 a, float4 b, float& ss) {
    ss += a.x * a.x + a.y * a.y + a.z * a.z + a.w * a.w
        + b.x * b.x + b.y * b.y + b.z * b.z + b.w * b.w;
    u32x4 u;
    u[0] = cvt_pk_bf16(a.x, a.y);
    u[1] = cvt_pk_bf16(a.z, a.w);
    u[2] = cvt_pk_bf16(b.x, b.y);
    u[3] = cvt_pk_bf16(b.z, b.w);
    return __builtin_bit_cast(short8, u);
}

// Fused ||q-p||^2 = qn + pn - 2*q.p. Block = 16q x 32p, 8 waves K-split 1024 -> 8x128.
// All 24 global_load_dwordx4 issue BEFORE any pack/MFMA: one HBM latency exposure,
// max memory-level parallelism at 2 waves/SIMD.
__global__ __launch_bounds__(512, 2)
void l2_fused(const float* __restrict__ proto,
              const float* __restrict__ query,
              float* __restrict__ out)
{
    __shared__ float dotl[NW][QB * DROW];   // 16.9 KB
    __shared__ float qnl[NW][QB];
    __shared__ float pnl[NW][PB];

    const int tid = threadIdx.x;
    const int bq  = blockIdx.x & 127;       // bid and bid+128 share the q-tile
    const int bp  = blockIdx.x >> 7;        //   -> same XCD under %8 round-robin
    const int q0  = bq * QB;
    const int p0  = bp * PB;
    const int w   = tid >> 6;               // wave id = K-slice id
    const int l   = tid & 63;
    const int lo  = l & 15;
    const int hi  = l >> 4;

    // A frag: lane l holds Q[q0+lo][w*KW + s*32 + hi*8 .. +7]
    // B frag: lane l holds P[p0+t*16+lo][same k range]
    const float* qrow  = query + (size_t)(q0 + lo) * DIM + w * KW + hi * 8;
    const float* prow0 = proto + (size_t)(p0 + lo) * DIM + w * KW + hi * 8;
    const float* prow1 = prow0 + (size_t)16 * DIM;

    // ---- bulk load phase: 24 dwordx4 in flight (96 VGPRs) ----
    float4 qa[8], pa[8], pb[8];
    #pragma unroll
    for (int s = 0; s < 4; ++s) {
        qa[2 * s]     = *(const float4*)(qrow + s * 32);
        qa[2 * s + 1] = *(const float4*)(qrow + s * 32 + 4);
    }
    #pragma unroll
    for (int s = 0; s < 4; ++s) {
        pa[2 * s]     = *(const float4*)(prow0 + s * 32);
        pa[2 * s + 1] = *(const float4*)(prow0 + s * 32 + 4);
    }
    #pragma unroll
    for (int s = 0; s < 4; ++s) {
        pb[2 * s]     = *(const float4*)(prow1 + s * 32);
        pb[2 * s + 1] = *(const float4*)(prow1 + s * 32 + 4);
    }

    // ---- compute phase ----
    f32x4 acc0 = {0.f, 0.f, 0.f, 0.f};
    f32x4 acc1 = {0.f, 0.f, 0.f, 0.f};
    float qn = 0.f, pn0 = 0.f, pn1 = 0.f;

    #pragma unroll
    for (int s = 0; s < 4; ++s) {
        short8 A  = pack8(qa[2 * s], qa[2 * s + 1], qn);
        short8 B0 = pack8(pa[2 * s], pa[2 * s + 1], pn0);
        short8 B1 = pack8(pb[2 * s], pb[2 * s + 1], pn1);
        acc0 = __builtin_amdgcn_mfma_f32_16x16x32_bf16(A, B0, acc0, 0, 0, 0);
        acc1 = __builtin_amdgcn_mfma_f32_16x16x32_bf16(A, B1, acc1, 0, 0, 0);
    }

    // reduce norm partials across the 4 hi-groups sharing a row
    qn  += __shfl_xor(qn, 16);  qn  += __shfl_xor(qn, 32);
    pn0 += __shfl_xor(pn0, 16); pn0 += __shfl_xor(pn0, 32);
    pn1 += __shfl_xor(pn1, 16); pn1 += __shfl_xor(pn1, 32);
    if (l < 16) {
        qnl[w][l]      = qn;
        pnl[w][l]      = pn0;
        pnl[w][l + 16] = pn1;
    }

    // D layout: col = l&15 (proto), row = (l>>4)*4 + r (query)
    #pragma unroll
    for (int r = 0; r < 4; ++r) {
        int q = hi * 4 + r;
        dotl[w][q * DROW + lo]      = acc0[r];
        dotl[w][q * DROW + lo + 16] = acc1[r];
    }
    __syncthreads();

    // epilogue: 512 threads -> 512 outputs of this block
    const int q = tid >> 5;
    const int p = tid & 31;
    float dsum = 0.f, qs = 0.f, ps = 0.f;
    #pragma unroll
    for (int k = 0; k < NW; ++k) {
        dsum += dotl[k][q * DROW + p];
        qs   += qnl[k][q];
        ps   += pnl[k][p];
    }
    out[(size_t)(q0 + q) * NP + p0 + p] = qs + ps - 2.f * dsum;
}

extern "C" void kernel_launch(void* const* d_in, const int* in_sizes, int n_in,
                              void* d_out, int out_size, void* d_ws, size_t ws_size,
                              hipStream_t stream) {
    const float* proto = (const float*)d_in[0];
    const float* query = (const float*)d_in[1];
    (void)d_ws; (void)ws_size;
    l2_fused<<<dim3((NQ / QB) * (NP / PB)), 512, 0, stream>>>(proto, query, (float*)d_out);
}